// Round 4
// baseline (686.831 us; speedup 1.0000x reference)
//
#include <hip/hip_runtime.h>

#define NUM_GRAPHS 1024
#define BIN_BITS 10
#define BIN_SIZE (1 << BIN_BITS)      // 1024 nodes per bin
#define EB 8192                       // edges per binning block
#define STH 512                       // scatter threads (8 waves)
#define EPT 16                        // edges per thread in scatter (EB/STH)
#define ATH 1024                      // accum threads

// ---------------------------------------------------------------------------
// Init: cursors to bin bases, zero pool accumulators.
// ---------------------------------------------------------------------------
__global__ void init_kernel(int* __restrict__ cursor, float* __restrict__ gsum,
                            float* __restrict__ gcnt, int cap) {
    int t = threadIdx.x;  // 1024
    if (t < 512) cursor[t] = t * cap;
    for (int j = t; j < NUM_GRAPHS * 4; j += 1024) gsum[j] = 0.0f;
    for (int j = t; j < NUM_GRAPHS; j += 1024) gcnt[j] = 0.0f;
}

// ---------------------------------------------------------------------------
// bin_scatter: per-block counting sort of 8192 edges by dst-bin in LDS, then
// coalesced flush of each bin segment to its reserved global region.
// dst kept in REGISTERS between count and place passes (saves 64 MB re-read).
// packed = (dst_local << 19) | src   (src < 2^19, dst_local < 2^10).
// Packed stores are non-temporal: written once, read once (by another XCD).
// ---------------------------------------------------------------------------
__global__ void __launch_bounds__(STH) bin_scatter(const int* __restrict__ src,
                                                   const int* __restrict__ dst,
                                                   int* __restrict__ packed,
                                                   int* __restrict__ cursor,
                                                   int E, int cap, int nb) {
    __shared__ int shist[512];     // counts, then running offsets for placement
    __shared__ int sprefix[513];   // exclusive prefix of counts
    __shared__ int sgbase[512];    // global base per bin (this block's slot)
    __shared__ int spacked[EB];    // bin-sorted packed edges (32 KB)
    __shared__ int wsum[8];

    const int t = threadIdx.x;
    const int lane = t & 63;
    const int wave = t >> 6;
    const int b0 = blockIdx.x * EB;
    const int myBase = b0 + t * EPT;

    for (int j = t; j < 512; j += STH) shist[j] = 0;
    __syncthreads();

    // ---- pass A: count bins; dst values stay in registers ----
    int4 dreg[EPT / 4];
    const bool full = (myBase + EPT <= E);
    if (full) {
#pragma unroll
        for (int v = 0; v < EPT / 4; ++v) {
            dreg[v] = *(const int4*)(dst + myBase + v * 4);
            atomicAdd(&shist[((unsigned)dreg[v].x) >> BIN_BITS], 1);
            atomicAdd(&shist[((unsigned)dreg[v].y) >> BIN_BITS], 1);
            atomicAdd(&shist[((unsigned)dreg[v].z) >> BIN_BITS], 1);
            atomicAdd(&shist[((unsigned)dreg[v].w) >> BIN_BITS], 1);
        }
    } else {
        for (int i = 0; i < EPT; ++i) {
            int e = myBase + i;
            if (e < E) atomicAdd(&shist[((unsigned)dst[e]) >> BIN_BITS], 1);
        }
    }
    __syncthreads();

    // ---- prefix scan of 512 counts (shfl within wave + cross-wave) ----
    {
        int v = shist[t];
        int inc = v;
#pragma unroll
        for (int off = 1; off < 64; off <<= 1) {
            int u = __shfl_up(inc, off);
            if (lane >= off) inc += u;
        }
        if (lane == 63) wsum[wave] = inc;
        __syncthreads();
        if (t == 0) {
            int acc = 0;
#pragma unroll
            for (int w = 0; w < 8; ++w) { int c = wsum[w]; wsum[w] = acc; acc += c; }
        }
        __syncthreads();
        int excl = inc - v + wsum[wave];       // exclusive prefix
        sprefix[t + 1] = excl + v;             // inclusive at t -> prefix[t+1]
        if (t == 0) sprefix[0] = 0;
        if (t < nb && v > 0) sgbase[t] = atomicAdd(&cursor[t], v);
        shist[t] = 0;                          // reuse as running offset
    }
    __syncthreads();

    // ---- pass B: place edges bin-sorted into LDS (dst from registers) ----
    if (full) {
#pragma unroll
        for (int v = 0; v < EPT / 4; ++v) {
            int4 s = *(const int4*)(src + myBase + v * 4);
            int bn, lp;
            bn = ((unsigned)dreg[v].x) >> BIN_BITS; lp = atomicAdd(&shist[bn], 1);
            spacked[sprefix[bn] + lp] = ((dreg[v].x & (BIN_SIZE - 1)) << 19) | s.x;
            bn = ((unsigned)dreg[v].y) >> BIN_BITS; lp = atomicAdd(&shist[bn], 1);
            spacked[sprefix[bn] + lp] = ((dreg[v].y & (BIN_SIZE - 1)) << 19) | s.y;
            bn = ((unsigned)dreg[v].z) >> BIN_BITS; lp = atomicAdd(&shist[bn], 1);
            spacked[sprefix[bn] + lp] = ((dreg[v].z & (BIN_SIZE - 1)) << 19) | s.z;
            bn = ((unsigned)dreg[v].w) >> BIN_BITS; lp = atomicAdd(&shist[bn], 1);
            spacked[sprefix[bn] + lp] = ((dreg[v].w & (BIN_SIZE - 1)) << 19) | s.w;
        }
    } else {
        for (int i = 0; i < EPT; ++i) {
            int e = myBase + i;
            if (e < E) {
                int d = dst[e];
                int bn = ((unsigned)d) >> BIN_BITS;
                int lp = atomicAdd(&shist[bn], 1);
                spacked[sprefix[bn] + lp] = ((d & (BIN_SIZE - 1)) << 19) | src[e];
            }
        }
    }
    __syncthreads();

    // ---- flush: bin segments -> contiguous global regions (coalesced, nt) ----
    int cnt = sprefix[nb < 512 ? nb : 512];
    int totE = E - b0; if (totE < 0) totE = 0;
    if (cnt > totE) cnt = totE;
    for (int j = t; j < cnt; j += STH) {
        int lo = 0, hi = nb;
        while (hi - lo > 1) {
            int mid = (lo + hi) >> 1;
            if (sprefix[mid] <= j) lo = mid; else hi = mid;
        }
        int pos = sgbase[lo] + (j - sprefix[lo]);
        if (pos < (lo + 1) * cap)              // overflow guard (~28 sigma)
            __builtin_nontemporal_store(spacked[j], &packed[pos]);
    }
}

// ---------------------------------------------------------------------------
// Fused accum + MLP + pool. One block per bin. TWO SWEEPS over the packed
// range by src half: sweep 0 touches x[0..N/2) (4 MB = one XCD L2), sweep 1
// the other half. All blocks sweep in the same order -> gathers hit L2.
// Packed reads are non-temporal so the stream doesn't evict x from L2.
// ---------------------------------------------------------------------------
__global__ void __launch_bounds__(ATH) bin_accum_mlp_pool(
        const float4* __restrict__ x,
        const int* __restrict__ packed,
        const int* __restrict__ cursor,
        const int* __restrict__ batch,
        const float* __restrict__ eps_p,
        const float* __restrict__ W1, const float* __restrict__ b1,
        const float* __restrict__ W2, const float* __restrict__ b2,
        float* __restrict__ gsum, float* __restrict__ gcnt,
        int N, int cap) {
    __shared__ float slice[BIN_SIZE * 5];   // 20 KB, stride-5 pad
    const int bin = blockIdx.x;
    const int t = threadIdx.x;

    for (int j = t; j < BIN_SIZE * 5; j += ATH) slice[j] = 0.0f;
    __syncthreads();

    const int start = bin * cap;
    int end = cursor[bin];
    if (end > start + cap) end = start + cap;
    const int Nhalf = (N + 1) >> 1;

#pragma unroll 1
    for (int sweep = 0; sweep < 2; ++sweep) {
        for (int e = start + t; e < end; e += 2 * ATH) {
            int p0 = __builtin_nontemporal_load(&packed[e]);
            int e1 = e + ATH;
            int p1 = (e1 < end) ? __builtin_nontemporal_load(&packed[e1]) : 0;
            bool v1 = (e1 < end);

            int s0 = p0 & 0x7FFFF;
            bool go0 = ((s0 < Nhalf) == (sweep == 0));
            int s1 = p1 & 0x7FFFF;
            bool go1 = v1 && ((s1 < Nhalf) == (sweep == 0));

            if (go0) {
                int dl = ((unsigned)p0) >> 19;
                float4 xv = x[s0];
                atomicAdd(&slice[dl * 5 + 0], xv.x);
                atomicAdd(&slice[dl * 5 + 1], xv.y);
                atomicAdd(&slice[dl * 5 + 2], xv.z);
                atomicAdd(&slice[dl * 5 + 3], xv.w);
            }
            if (go1) {
                int dl = ((unsigned)p1) >> 19;
                float4 xv = x[s1];
                atomicAdd(&slice[dl * 5 + 0], xv.x);
                atomicAdd(&slice[dl * 5 + 1], xv.y);
                atomicAdd(&slice[dl * 5 + 2], xv.z);
                atomicAdd(&slice[dl * 5 + 3], xv.w);
            }
        }
        __syncthreads();
    }

    // ---- MLP + pool directly from the LDS slice ----
    int n = bin * BIN_SIZE + t;           // one node per thread
    bool valid = n < N;
    float o0 = 0.f, o1 = 0.f, o2 = 0.f, o3 = 0.f;
    int g = -1;
    if (valid) {
        float eps = eps_p[0];
        float4 xv = x[n];
        float h0 = (1.0f + eps) * xv.x + slice[t * 5 + 0];
        float h1 = (1.0f + eps) * xv.y + slice[t * 5 + 1];
        float h2 = (1.0f + eps) * xv.z + slice[t * 5 + 2];
        float h3 = (1.0f + eps) * xv.w + slice[t * 5 + 3];

        float tmp[16];
#pragma unroll
        for (int j = 0; j < 16; ++j) {
            float v = b1[j] + h0 * W1[j] + h1 * W1[16 + j] + h2 * W1[32 + j] + h3 * W1[48 + j];
            tmp[j] = v > 0.0f ? v : 0.0f;
        }
        float o[4];
#pragma unroll
        for (int j = 0; j < 4; ++j) {
            float v = b2[j];
#pragma unroll
            for (int k = 0; k < 16; ++k) v += tmp[k] * W2[k * 4 + j];
            o[j] = v > 0.0f ? v : 0.0f;
        }
        o0 = o[0]; o1 = o[1]; o2 = o[2]; o3 = o[3];
        g = batch[n];
    }

    // batch is sorted -> waves almost always graph-uniform
    int g0 = __shfl(g, 0);
    bool uni = __all(g == g0);
    if (uni && g0 >= 0) {
#pragma unroll
        for (int off = 32; off > 0; off >>= 1) {
            o0 += __shfl_down(o0, off);
            o1 += __shfl_down(o1, off);
            o2 += __shfl_down(o2, off);
            o3 += __shfl_down(o3, off);
        }
        if ((t & 63) == 0) {
            unsafeAtomicAdd(&gsum[(size_t)g0 * 4 + 0], o0);
            unsafeAtomicAdd(&gsum[(size_t)g0 * 4 + 1], o1);
            unsafeAtomicAdd(&gsum[(size_t)g0 * 4 + 2], o2);
            unsafeAtomicAdd(&gsum[(size_t)g0 * 4 + 3], o3);
            unsafeAtomicAdd(&gcnt[g0], 64.0f);
        }
    } else if (valid) {
        unsafeAtomicAdd(&gsum[(size_t)g * 4 + 0], o0);
        unsafeAtomicAdd(&gsum[(size_t)g * 4 + 1], o1);
        unsafeAtomicAdd(&gsum[(size_t)g * 4 + 2], o2);
        unsafeAtomicAdd(&gsum[(size_t)g * 4 + 3], o3);
        unsafeAtomicAdd(&gcnt[g], 1.0f);
    }
}

// ---------------------------------------------------------------------------
// pooled = sums / max(cnt,1); out = log_softmax per graph.
// ---------------------------------------------------------------------------
__global__ void pool_softmax_kernel(const float* __restrict__ gsum,
                                    const float* __restrict__ gcnt,
                                    float* __restrict__ out) {
    int g = blockIdx.x * blockDim.x + threadIdx.x;
    if (g >= NUM_GRAPHS) return;
    float c = fmaxf(gcnt[g], 1.0f);
    float p0 = gsum[g * 4 + 0] / c;
    float p1 = gsum[g * 4 + 1] / c;
    float p2 = gsum[g * 4 + 2] / c;
    float p3 = gsum[g * 4 + 3] / c;
    float m = fmaxf(fmaxf(p0, p1), fmaxf(p2, p3));
    float s = expf(p0 - m) + expf(p1 - m) + expf(p2 - m) + expf(p3 - m);
    float lse = m + logf(s);
    out[g * 4 + 0] = p0 - lse;
    out[g * 4 + 1] = p1 - lse;
    out[g * 4 + 2] = p2 - lse;
    out[g * 4 + 3] = p3 - lse;
}

// ---------------------------------------------------------------------------
// Fallback kernels (ws too small): direct atomic scatter + separate MLP/pool.
// ---------------------------------------------------------------------------
__global__ void edge_scatter_kernel(const float4* __restrict__ x,
                                    const int* __restrict__ src,
                                    const int* __restrict__ dst,
                                    float* __restrict__ agg,
                                    int E) {
    int t = blockIdx.x * blockDim.x + threadIdx.x;
    int e = t * 4;
    if (e + 3 < E) {
        int4 s = *(const int4*)(src + e);
        int4 d = *(const int4*)(dst + e);
        float4 xv;
        xv = x[s.x];
        unsafeAtomicAdd(&agg[(size_t)d.x * 4 + 0], xv.x);
        unsafeAtomicAdd(&agg[(size_t)d.x * 4 + 1], xv.y);
        unsafeAtomicAdd(&agg[(size_t)d.x * 4 + 2], xv.z);
        unsafeAtomicAdd(&agg[(size_t)d.x * 4 + 3], xv.w);
        xv = x[s.y];
        unsafeAtomicAdd(&agg[(size_t)d.y * 4 + 0], xv.x);
        unsafeAtomicAdd(&agg[(size_t)d.y * 4 + 1], xv.y);
        unsafeAtomicAdd(&agg[(size_t)d.y * 4 + 2], xv.z);
        unsafeAtomicAdd(&agg[(size_t)d.y * 4 + 3], xv.w);
        xv = x[s.z];
        unsafeAtomicAdd(&agg[(size_t)d.z * 4 + 0], xv.x);
        unsafeAtomicAdd(&agg[(size_t)d.z * 4 + 1], xv.y);
        unsafeAtomicAdd(&agg[(size_t)d.z * 4 + 2], xv.z);
        unsafeAtomicAdd(&agg[(size_t)d.z * 4 + 3], xv.w);
        xv = x[s.w];
        unsafeAtomicAdd(&agg[(size_t)d.w * 4 + 0], xv.x);
        unsafeAtomicAdd(&agg[(size_t)d.w * 4 + 1], xv.y);
        unsafeAtomicAdd(&agg[(size_t)d.w * 4 + 2], xv.z);
        unsafeAtomicAdd(&agg[(size_t)d.w * 4 + 3], xv.w);
    } else {
        for (int i = e; i < E; ++i) {
            int sv = src[i], dv = dst[i];
            float4 xv = x[sv];
            unsafeAtomicAdd(&agg[(size_t)dv * 4 + 0], xv.x);
            unsafeAtomicAdd(&agg[(size_t)dv * 4 + 1], xv.y);
            unsafeAtomicAdd(&agg[(size_t)dv * 4 + 2], xv.z);
            unsafeAtomicAdd(&agg[(size_t)dv * 4 + 3], xv.w);
        }
    }
}

__global__ void node_mlp_pool_kernel(const float4* __restrict__ x,
                                     const float4* __restrict__ agg,
                                     const int* __restrict__ batch,
                                     const float* __restrict__ eps_p,
                                     const float* __restrict__ W1,
                                     const float* __restrict__ b1,
                                     const float* __restrict__ W2,
                                     const float* __restrict__ b2,
                                     float* __restrict__ gsum,
                                     float* __restrict__ gcnt,
                                     int N) {
    int i = blockIdx.x * blockDim.x + threadIdx.x;
    bool valid = i < N;
    float o0 = 0.f, o1 = 0.f, o2 = 0.f, o3 = 0.f;
    int g = -1;
    if (valid) {
        float eps = eps_p[0];
        float4 xv = x[i];
        float4 av = agg[i];
        float h0 = (1.0f + eps) * xv.x + av.x;
        float h1 = (1.0f + eps) * xv.y + av.y;
        float h2 = (1.0f + eps) * xv.z + av.z;
        float h3 = (1.0f + eps) * xv.w + av.w;
        float tmp[16];
#pragma unroll
        for (int j = 0; j < 16; ++j) {
            float v = b1[j] + h0 * W1[j] + h1 * W1[16 + j] + h2 * W1[32 + j] + h3 * W1[48 + j];
            tmp[j] = v > 0.0f ? v : 0.0f;
        }
        float o[4];
#pragma unroll
        for (int j = 0; j < 4; ++j) {
            float v = b2[j];
#pragma unroll
            for (int k = 0; k < 16; ++k) v += tmp[k] * W2[k * 4 + j];
            o[j] = v > 0.0f ? v : 0.0f;
        }
        o0 = o[0]; o1 = o[1]; o2 = o[2]; o3 = o[3];
        g = batch[i];
    }
    int g0 = __shfl(g, 0);
    bool uni = __all(g == g0);
    if (uni && g0 >= 0) {
#pragma unroll
        for (int off = 32; off > 0; off >>= 1) {
            o0 += __shfl_down(o0, off);
            o1 += __shfl_down(o1, off);
            o2 += __shfl_down(o2, off);
            o3 += __shfl_down(o3, off);
        }
        if ((threadIdx.x & 63) == 0) {
            unsafeAtomicAdd(&gsum[(size_t)g0 * 4 + 0], o0);
            unsafeAtomicAdd(&gsum[(size_t)g0 * 4 + 1], o1);
            unsafeAtomicAdd(&gsum[(size_t)g0 * 4 + 2], o2);
            unsafeAtomicAdd(&gsum[(size_t)g0 * 4 + 3], o3);
            unsafeAtomicAdd(&gcnt[g0], 64.0f);
        }
    } else if (valid) {
        unsafeAtomicAdd(&gsum[(size_t)g * 4 + 0], o0);
        unsafeAtomicAdd(&gsum[(size_t)g * 4 + 1], o1);
        unsafeAtomicAdd(&gsum[(size_t)g * 4 + 2], o2);
        unsafeAtomicAdd(&gsum[(size_t)g * 4 + 3], o3);
        unsafeAtomicAdd(&gcnt[g], 1.0f);
    }
}

extern "C" void kernel_launch(void* const* d_in, const int* in_sizes, int n_in,
                              void* d_out, int out_size, void* d_ws, size_t ws_size,
                              hipStream_t stream) {
    const float* x     = (const float*)d_in[0];
    const int*   ei    = (const int*)d_in[1];
    const int*   batch = (const int*)d_in[2];
    const float* eps   = (const float*)d_in[3];
    const float* W1    = (const float*)d_in[4];
    const float* b1    = (const float*)d_in[5];
    const float* W2    = (const float*)d_in[6];
    const float* b2    = (const float*)d_in[7];

    const int N = in_sizes[0] / 4;
    const int E = in_sizes[1] / 2;
    const int* src = ei;
    const int* dst = ei + (size_t)E;

    const int nb = (N + BIN_SIZE - 1) >> BIN_BITS;   // 489 for N=500K
    const int epb = (E + nb - 1) / nb;
    const int cap = epb + epb / 8 + 1024;            // ~28 sigma headroom

    // Fast-path ws layout: packed [nb*cap] | cursor [512] | gsum [G*4] | gcnt [G]
    size_t packed_elems = ((size_t)nb * cap + 3) & ~(size_t)3;
    size_t need = (packed_elems + 512 + NUM_GRAPHS * 4 + NUM_GRAPHS) * sizeof(float);

    if (nb <= 512 && N < (1 << 19) && need <= ws_size) {
        int*   packed = (int*)d_ws;
        int*   cursor = (int*)d_ws + packed_elems;
        float* gsum   = (float*)(cursor + 512);
        float* gcnt   = gsum + (size_t)NUM_GRAPHS * 4;

        init_kernel<<<1, 1024, 0, stream>>>(cursor, gsum, gcnt, cap);

        int nblocks_e = (E + EB - 1) / EB;
        bin_scatter<<<nblocks_e, STH, 0, stream>>>(src, dst, packed, cursor, E, cap, nb);

        bin_accum_mlp_pool<<<nb, ATH, 0, stream>>>(
            (const float4*)x, packed, cursor, batch, eps, W1, b1, W2, b2,
            gsum, gcnt, N, cap);

        pool_softmax_kernel<<<(NUM_GRAPHS + 255) / 256, 256, 0, stream>>>(
            gsum, gcnt, (float*)d_out);
    } else {
        float* agg  = (float*)d_ws;
        float* gsum = agg + (size_t)N * 4;
        float* gcnt = gsum + (size_t)NUM_GRAPHS * 4;
        size_t zero_bytes = ((size_t)N * 4 + NUM_GRAPHS * 5) * sizeof(float);
        hipMemsetAsync(d_ws, 0, zero_bytes, stream);

        int e4 = (E + 3) / 4;
        edge_scatter_kernel<<<(e4 + 255) / 256, 256, 0, stream>>>(
            (const float4*)x, src, dst, agg, E);

        node_mlp_pool_kernel<<<(N + 255) / 256, 256, 0, stream>>>(
            (const float4*)x, (const float4*)agg, batch, eps, W1, b1, W2, b2,
            gsum, gcnt, N);

        pool_softmax_kernel<<<(NUM_GRAPHS + 255) / 256, 256, 0, stream>>>(
            gsum, gcnt, (float*)d_out);
    }
}

// Round 6
// 515.920 us; speedup vs baseline: 1.3313x; 1.3313x over previous
//
#include <hip/hip_runtime.h>

#define NUM_GRAPHS 1024
#define BIN_BITS 10
#define BIN_SIZE (1 << BIN_BITS)      // 1024 nodes per bin
#define EB 8192                       // edges per binning block
#define STH 512                       // scatter threads (8 waves)
#define EPT 16                        // edges per thread in scatter (EB/STH)
#define ATH 1024                      // accum threads (= nodes per bin)
#define ACH 8192                      // accum chunk edges
#define AEPT (ACH / ATH)              // 8 edges per thread per chunk

// ---------------------------------------------------------------------------
// Init: cursors to bin bases, zero pool accumulators.
// ---------------------------------------------------------------------------
__global__ void init_kernel(int* __restrict__ cursor, float* __restrict__ gsum,
                            float* __restrict__ gcnt, int cap) {
    int t = threadIdx.x;  // 1024
    if (t < 512) cursor[t] = t * cap;
    for (int j = t; j < NUM_GRAPHS * 4; j += 1024) gsum[j] = 0.0f;
    for (int j = t; j < NUM_GRAPHS; j += 1024) gcnt[j] = 0.0f;
}

// ---------------------------------------------------------------------------
// bin_scatter v3: ONE histogram pass with returning LDS atomics — rtn value
// is the local position, kept in registers with the packed edge; placement
// is plain LDS writes. 16M lane-atomics (was 32M; DS atomics ~3.9 cyc/lane
// are the bottleneck, r4 model).
// packed = (dst_local << 19) | src   (src < 2^19, dst_local < 2^10).
// ---------------------------------------------------------------------------
__global__ void __launch_bounds__(STH) bin_scatter(const int* __restrict__ src,
                                                   const int* __restrict__ dst,
                                                   int* __restrict__ packed,
                                                   int* __restrict__ cursor,
                                                   int E, int cap, int nb) {
    __shared__ int shist[512];     // per-bin counts (via rtn atomics)
    __shared__ int sprefix[513];   // exclusive prefix of counts
    __shared__ int sgbase[512];    // global base per bin (this block's slot)
    __shared__ int spacked[EB];    // bin-sorted packed edges (32 KB)
    __shared__ int wsum[8];

    const int t = threadIdx.x;
    const int lane = t & 63;
    const int wave = t >> 6;
    const int b0 = blockIdx.x * EB;
    const int myBase = b0 + t * EPT;

    for (int j = t; j < 512; j += STH) shist[j] = 0;
    __syncthreads();

    // ---- pass A: rtn-atomic count -> (bin,lpos) + packed value in registers
    int pv[EPT];                   // packed edge values
    int bl[EPT];                   // (bin << 13) | lpos   (lpos < 8192)
    int cntMine = 0;
    const bool full = (myBase + EPT <= E);
    if (full) {
#pragma unroll
        for (int v = 0; v < EPT / 4; ++v) {
            int4 d = *(const int4*)(dst + myBase + v * 4);
            int4 s = *(const int4*)(src + myBase + v * 4);
            int bn, lp;
            bn = ((unsigned)d.x) >> BIN_BITS; lp = atomicAdd(&shist[bn], 1);
            pv[v * 4 + 0] = ((d.x & (BIN_SIZE - 1)) << 19) | s.x;
            bl[v * 4 + 0] = (bn << 13) | lp;
            bn = ((unsigned)d.y) >> BIN_BITS; lp = atomicAdd(&shist[bn], 1);
            pv[v * 4 + 1] = ((d.y & (BIN_SIZE - 1)) << 19) | s.y;
            bl[v * 4 + 1] = (bn << 13) | lp;
            bn = ((unsigned)d.z) >> BIN_BITS; lp = atomicAdd(&shist[bn], 1);
            pv[v * 4 + 2] = ((d.z & (BIN_SIZE - 1)) << 19) | s.z;
            bl[v * 4 + 2] = (bn << 13) | lp;
            bn = ((unsigned)d.w) >> BIN_BITS; lp = atomicAdd(&shist[bn], 1);
            pv[v * 4 + 3] = ((d.w & (BIN_SIZE - 1)) << 19) | s.w;
            bl[v * 4 + 3] = (bn << 13) | lp;
        }
        cntMine = EPT;
    } else {
        for (int i = 0; i < EPT; ++i) {
            int e = myBase + i;
            if (e < E) {
                int d = dst[e];
                int bn = ((unsigned)d) >> BIN_BITS;
                int lp = atomicAdd(&shist[bn], 1);
                pv[cntMine] = ((d & (BIN_SIZE - 1)) << 19) | src[e];
                bl[cntMine] = (bn << 13) | lp;
                ++cntMine;
            }
        }
    }
    __syncthreads();

    // ---- prefix scan of 512 counts (shfl within wave + cross-wave) ----
    {
        int v = shist[t];
        int inc = v;
#pragma unroll
        for (int off = 1; off < 64; off <<= 1) {
            int u = __shfl_up(inc, off);
            if (lane >= off) inc += u;
        }
        if (lane == 63) wsum[wave] = inc;
        __syncthreads();
        if (t == 0) {
            int acc = 0;
#pragma unroll
            for (int w = 0; w < 8; ++w) { int c = wsum[w]; wsum[w] = acc; acc += c; }
        }
        __syncthreads();
        sprefix[t + 1] = inc + wsum[wave];     // inclusive prefix at t
        if (t == 0) sprefix[0] = 0;
        if (t < nb && v > 0) sgbase[t] = atomicAdd(&cursor[t], v);
    }
    __syncthreads();

    // ---- pass B: place from registers — PLAIN LDS writes, no atomics ----
    for (int i = 0; i < cntMine; ++i) {
        int bn = ((unsigned)bl[i]) >> 13;
        int lp = bl[i] & 0x1FFF;
        spacked[sprefix[bn] + lp] = pv[i];
    }
    __syncthreads();

    // ---- flush: bin segments -> contiguous global regions (coalesced, nt) ----
    int cnt = sprefix[nb < 512 ? nb : 512];
    int totE = E - b0; if (totE < 0) totE = 0;
    if (cnt > totE) cnt = totE;
    for (int j = t; j < cnt; j += STH) {
        int lo = 0, hi = nb;
        while (hi - lo > 1) {
            int mid = (lo + hi) >> 1;
            if (sprefix[mid] <= j) lo = mid; else hi = mid;
        }
        int pos = sgbase[lo] + (j - sprefix[lo]);
        if (pos < (lo + 1) * cap)              // overflow guard (~28 sigma)
            __builtin_nontemporal_store(spacked[j], &packed[pos]);
    }
}

// ---------------------------------------------------------------------------
// Accum v3 + MLP + pool, one block per bin. Per 8192-edge chunk:
//   rtn-atomic histogram over dst_local (the ONLY atomics: 16M total, was
//   64M ds_add_f32) -> 1024-wide prefix scan -> place src by plain LDS write
//   -> thread t consumes its node's contiguous segment, accumulating x[src]
//   into REGISTERS. Consume runs as two src-half sweeps so the x gather
//   stays XCD-L2-resident (r4: FETCH 543->151 MB).
// ---------------------------------------------------------------------------
__global__ void __launch_bounds__(ATH) bin_accum_mlp_pool(
        const float4* __restrict__ x,
        const int* __restrict__ packed,
        const int* __restrict__ cursor,
        const int* __restrict__ batch,
        const float* __restrict__ eps_p,
        const float* __restrict__ W1, const float* __restrict__ b1,
        const float* __restrict__ W2, const float* __restrict__ b2,
        float* __restrict__ gsum, float* __restrict__ gcnt,
        int N, int cap) {
    __shared__ int srt[ACH];            // 32 KB: src ids sorted by dst_local
    __shared__ int hist[BIN_SIZE];      // 4 KB
    __shared__ int pfx[BIN_SIZE + 1];   // 4 KB
    __shared__ int wsum[16];

    const int bin = blockIdx.x;
    const int t = threadIdx.x;
    const int lane = t & 63;
    const int wave = t >> 6;

    const int start = bin * cap;
    int end = cursor[bin];
    if (end > start + cap) end = start + cap;
    const int Nhalf = (N + 1) >> 1;

    float a0 = 0.f, a1 = 0.f, a2 = 0.f, a3 = 0.f;   // agg for node bin*1024+t

#pragma unroll 1
    for (int cs = start; cs < end; cs += ACH) {
        int ce = cs + ACH; if (ce > end) ce = end;

        hist[t] = 0;
        __syncthreads();

        // ---- histogram with rtn atomics; edge data stays in registers ----
        int dlp[AEPT];   // (dst_local << 13) | lpos
        int sv[AEPT];    // src id
        int m = 0;
#pragma unroll
        for (int i = 0; i < AEPT; ++i) {
            int e = cs + i * ATH + t;
            if (e < ce) {
                int p = __builtin_nontemporal_load(&packed[e]);
                int dl = ((unsigned)p) >> 19;
                int lp = atomicAdd(&hist[dl], 1);
                dlp[m] = (dl << 13) | lp;
                sv[m] = p & 0x7FFFF;
                ++m;
            }
        }
        __syncthreads();

        // ---- prefix scan over 1024 counts ----
        {
            int v = hist[t];
            int inc = v;
#pragma unroll
            for (int off = 1; off < 64; off <<= 1) {
                int u = __shfl_up(inc, off);
                if (lane >= off) inc += u;
            }
            if (lane == 63) wsum[wave] = inc;
            __syncthreads();
            if (t == 0) {
                int acc = 0;
#pragma unroll
                for (int w = 0; w < 16; ++w) { int c = wsum[w]; wsum[w] = acc; acc += c; }
            }
            __syncthreads();
            pfx[t + 1] = inc + wsum[wave];
            if (t == 0) pfx[0] = 0;
        }
        __syncthreads();

        // ---- place src ids sorted by dst_local — plain LDS writes ----
        for (int i = 0; i < m; ++i) {
            int dl = ((unsigned)dlp[i]) >> 13;
            int lp = dlp[i] & 0x1FFF;
            srt[pfx[dl] + lp] = sv[i];
        }
        __syncthreads();

        // ---- consume own segment into registers; two src-half sweeps ----
        int jb = pfx[t], je = pfx[t + 1];
#pragma unroll 1
        for (int sweep = 0; sweep < 2; ++sweep) {
            for (int j = jb; j < je; ++j) {
                int s = srt[j];
                if ((s < Nhalf) == (sweep == 0)) {
                    float4 xv = x[s];
                    a0 += xv.x; a1 += xv.y; a2 += xv.z; a3 += xv.w;
                }
            }
        }
        __syncthreads();   // protect srt/hist before next chunk
    }

    // ---- MLP + pool from register accumulator ----
    int n = bin * BIN_SIZE + t;           // one node per thread
    bool valid = n < N;
    float o0 = 0.f, o1 = 0.f, o2 = 0.f, o3 = 0.f;
    int g = -1;
    if (valid) {
        float eps = eps_p[0];
        float4 xv = x[n];
        float h0 = (1.0f + eps) * xv.x + a0;
        float h1 = (1.0f + eps) * xv.y + a1;
        float h2 = (1.0f + eps) * xv.z + a2;
        float h3 = (1.0f + eps) * xv.w + a3;

        float tmp[16];
#pragma unroll
        for (int j = 0; j < 16; ++j) {
            float v = b1[j] + h0 * W1[j] + h1 * W1[16 + j] + h2 * W1[32 + j] + h3 * W1[48 + j];
            tmp[j] = v > 0.0f ? v : 0.0f;
        }
        float o[4];
#pragma unroll
        for (int j = 0; j < 4; ++j) {
            float v = b2[j];
#pragma unroll
            for (int k = 0; k < 16; ++k) v += tmp[k] * W2[k * 4 + j];
            o[j] = v > 0.0f ? v : 0.0f;
        }
        o0 = o[0]; o1 = o[1]; o2 = o[2]; o3 = o[3];
        g = batch[n];
    }

    // batch is sorted -> waves almost always graph-uniform
    int g0 = __shfl(g, 0);
    bool uni = __all(g == g0);
    if (uni && g0 >= 0) {
#pragma unroll
        for (int off = 32; off > 0; off >>= 1) {
            o0 += __shfl_down(o0, off);
            o1 += __shfl_down(o1, off);
            o2 += __shfl_down(o2, off);
            o3 += __shfl_down(o3, off);
        }
        if ((t & 63) == 0) {
            unsafeAtomicAdd(&gsum[(size_t)g0 * 4 + 0], o0);
            unsafeAtomicAdd(&gsum[(size_t)g0 * 4 + 1], o1);
            unsafeAtomicAdd(&gsum[(size_t)g0 * 4 + 2], o2);
            unsafeAtomicAdd(&gsum[(size_t)g0 * 4 + 3], o3);
            unsafeAtomicAdd(&gcnt[g0], 64.0f);
        }
    } else if (valid) {
        unsafeAtomicAdd(&gsum[(size_t)g * 4 + 0], o0);
        unsafeAtomicAdd(&gsum[(size_t)g * 4 + 1], o1);
        unsafeAtomicAdd(&gsum[(size_t)g * 4 + 2], o2);
        unsafeAtomicAdd(&gsum[(size_t)g * 4 + 3], o3);
        unsafeAtomicAdd(&gcnt[g], 1.0f);
    }
}

// ---------------------------------------------------------------------------
// pooled = sums / max(cnt,1); out = log_softmax per graph.
// ---------------------------------------------------------------------------
__global__ void pool_softmax_kernel(const float* __restrict__ gsum,
                                    const float* __restrict__ gcnt,
                                    float* __restrict__ out) {
    int g = blockIdx.x * blockDim.x + threadIdx.x;
    if (g >= NUM_GRAPHS) return;
    float c = fmaxf(gcnt[g], 1.0f);
    float p0 = gsum[g * 4 + 0] / c;
    float p1 = gsum[g * 4 + 1] / c;
    float p2 = gsum[g * 4 + 2] / c;
    float p3 = gsum[g * 4 + 3] / c;
    float m = fmaxf(fmaxf(p0, p1), fmaxf(p2, p3));
    float s = expf(p0 - m) + expf(p1 - m) + expf(p2 - m) + expf(p3 - m);
    float lse = m + logf(s);
    out[g * 4 + 0] = p0 - lse;
    out[g * 4 + 1] = p1 - lse;
    out[g * 4 + 2] = p2 - lse;
    out[g * 4 + 3] = p3 - lse;
}

// ---------------------------------------------------------------------------
// Fallback kernels (ws too small): direct atomic scatter + separate MLP/pool.
// ---------------------------------------------------------------------------
__global__ void edge_scatter_kernel(const float4* __restrict__ x,
                                    const int* __restrict__ src,
                                    const int* __restrict__ dst,
                                    float* __restrict__ agg,
                                    int E) {
    int t = blockIdx.x * blockDim.x + threadIdx.x;
    int e = t * 4;
    if (e + 3 < E) {
        int4 s = *(const int4*)(src + e);
        int4 d = *(const int4*)(dst + e);
        float4 xv;
        xv = x[s.x];
        unsafeAtomicAdd(&agg[(size_t)d.x * 4 + 0], xv.x);
        unsafeAtomicAdd(&agg[(size_t)d.x * 4 + 1], xv.y);
        unsafeAtomicAdd(&agg[(size_t)d.x * 4 + 2], xv.z);
        unsafeAtomicAdd(&agg[(size_t)d.x * 4 + 3], xv.w);
        xv = x[s.y];
        unsafeAtomicAdd(&agg[(size_t)d.y * 4 + 0], xv.x);
        unsafeAtomicAdd(&agg[(size_t)d.y * 4 + 1], xv.y);
        unsafeAtomicAdd(&agg[(size_t)d.y * 4 + 2], xv.z);
        unsafeAtomicAdd(&agg[(size_t)d.y * 4 + 3], xv.w);
        xv = x[s.z];
        unsafeAtomicAdd(&agg[(size_t)d.z * 4 + 0], xv.x);
        unsafeAtomicAdd(&agg[(size_t)d.z * 4 + 1], xv.y);
        unsafeAtomicAdd(&agg[(size_t)d.z * 4 + 2], xv.z);
        unsafeAtomicAdd(&agg[(size_t)d.z * 4 + 3], xv.w);
        xv = x[s.w];
        unsafeAtomicAdd(&agg[(size_t)d.w * 4 + 0], xv.x);
        unsafeAtomicAdd(&agg[(size_t)d.w * 4 + 1], xv.y);
        unsafeAtomicAdd(&agg[(size_t)d.w * 4 + 2], xv.z);
        unsafeAtomicAdd(&agg[(size_t)d.w * 4 + 3], xv.w);
    } else {
        for (int i = e; i < E; ++i) {
            int sv = src[i], dv = dst[i];
            float4 xv = x[sv];
            unsafeAtomicAdd(&agg[(size_t)dv * 4 + 0], xv.x);
            unsafeAtomicAdd(&agg[(size_t)dv * 4 + 1], xv.y);
            unsafeAtomicAdd(&agg[(size_t)dv * 4 + 2], xv.z);
            unsafeAtomicAdd(&agg[(size_t)dv * 4 + 3], xv.w);
        }
    }
}

__global__ void node_mlp_pool_kernel(const float4* __restrict__ x,
                                     const float4* __restrict__ agg,
                                     const int* __restrict__ batch,
                                     const float* __restrict__ eps_p,
                                     const float* __restrict__ W1,
                                     const float* __restrict__ b1,
                                     const float* __restrict__ W2,
                                     const float* __restrict__ b2,
                                     float* __restrict__ gsum,
                                     float* __restrict__ gcnt,
                                     int N) {
    int i = blockIdx.x * blockDim.x + threadIdx.x;
    bool valid = i < N;
    float o0 = 0.f, o1 = 0.f, o2 = 0.f, o3 = 0.f;
    int g = -1;
    if (valid) {
        float eps = eps_p[0];
        float4 xv = x[i];
        float4 av = agg[i];
        float h0 = (1.0f + eps) * xv.x + av.x;
        float h1 = (1.0f + eps) * xv.y + av.y;
        float h2 = (1.0f + eps) * xv.z + av.z;
        float h3 = (1.0f + eps) * xv.w + av.w;
        float tmp[16];
#pragma unroll
        for (int j = 0; j < 16; ++j) {
            float v = b1[j] + h0 * W1[j] + h1 * W1[16 + j] + h2 * W1[32 + j] + h3 * W1[48 + j];
            tmp[j] = v > 0.0f ? v : 0.0f;
        }
        float o[4];
#pragma unroll
        for (int j = 0; j < 4; ++j) {
            float v = b2[j];
#pragma unroll
            for (int k = 0; k < 16; ++k) v += tmp[k] * W2[k * 4 + j];
            o[j] = v > 0.0f ? v : 0.0f;
        }
        o0 = o[0]; o1 = o[1]; o2 = o[2]; o3 = o[3];
        g = batch[i];
    }
    int g0 = __shfl(g, 0);
    bool uni = __all(g == g0);
    if (uni && g0 >= 0) {
#pragma unroll
        for (int off = 32; off > 0; off >>= 1) {
            o0 += __shfl_down(o0, off);
            o1 += __shfl_down(o1, off);
            o2 += __shfl_down(o2, off);
            o3 += __shfl_down(o3, off);
        }
        if ((threadIdx.x & 63) == 0) {
            unsafeAtomicAdd(&gsum[(size_t)g0 * 4 + 0], o0);
            unsafeAtomicAdd(&gsum[(size_t)g0 * 4 + 1], o1);
            unsafeAtomicAdd(&gsum[(size_t)g0 * 4 + 2], o2);
            unsafeAtomicAdd(&gsum[(size_t)g0 * 4 + 3], o3);
            unsafeAtomicAdd(&gcnt[g0], 64.0f);
        }
    } else if (valid) {
        unsafeAtomicAdd(&gsum[(size_t)g * 4 + 0], o0);
        unsafeAtomicAdd(&gsum[(size_t)g * 4 + 1], o1);
        unsafeAtomicAdd(&gsum[(size_t)g * 4 + 2], o2);
        unsafeAtomicAdd(&gsum[(size_t)g * 4 + 3], o3);
        unsafeAtomicAdd(&gcnt[g], 1.0f);
    }
}

extern "C" void kernel_launch(void* const* d_in, const int* in_sizes, int n_in,
                              void* d_out, int out_size, void* d_ws, size_t ws_size,
                              hipStream_t stream) {
    const float* x     = (const float*)d_in[0];
    const int*   ei    = (const int*)d_in[1];
    const int*   batch = (const int*)d_in[2];
    const float* eps   = (const float*)d_in[3];
    const float* W1    = (const float*)d_in[4];
    const float* b1    = (const float*)d_in[5];
    const float* W2    = (const float*)d_in[6];
    const float* b2    = (const float*)d_in[7];

    const int N = in_sizes[0] / 4;
    const int E = in_sizes[1] / 2;
    const int* src = ei;
    const int* dst = ei + (size_t)E;

    const int nb = (N + BIN_SIZE - 1) >> BIN_BITS;   // 489 for N=500K
    const int epb = (E + nb - 1) / nb;
    const int cap = epb + epb / 8 + 1024;            // ~28 sigma headroom

    // Fast-path ws layout: packed [nb*cap] | cursor [512] | gsum [G*4] | gcnt [G]
    size_t packed_elems = ((size_t)nb * cap + 3) & ~(size_t)3;
    size_t need = (packed_elems + 512 + NUM_GRAPHS * 4 + NUM_GRAPHS) * sizeof(float);

    if (nb <= 512 && N < (1 << 19) && need <= ws_size) {
        int*   packed = (int*)d_ws;
        int*   cursor = (int*)d_ws + packed_elems;
        float* gsum   = (float*)(cursor + 512);
        float* gcnt   = gsum + (size_t)NUM_GRAPHS * 4;

        init_kernel<<<1, 1024, 0, stream>>>(cursor, gsum, gcnt, cap);

        int nblocks_e = (E + EB - 1) / EB;
        bin_scatter<<<nblocks_e, STH, 0, stream>>>(src, dst, packed, cursor, E, cap, nb);

        bin_accum_mlp_pool<<<nb, ATH, 0, stream>>>(
            (const float4*)x, packed, cursor, batch, eps, W1, b1, W2, b2,
            gsum, gcnt, N, cap);

        pool_softmax_kernel<<<(NUM_GRAPHS + 255) / 256, 256, 0, stream>>>(
            gsum, gcnt, (float*)d_out);
    } else {
        float* agg  = (float*)d_ws;
        float* gsum = agg + (size_t)N * 4;
        float* gcnt = gsum + (size_t)NUM_GRAPHS * 4;
        size_t zero_bytes = ((size_t)N * 4 + NUM_GRAPHS * 5) * sizeof(float);
        (void)hipMemsetAsync(d_ws, 0, zero_bytes, stream);

        int e4 = (E + 3) / 4;
        edge_scatter_kernel<<<(e4 + 255) / 256, 256, 0, stream>>>(
            (const float4*)x, src, dst, agg, E);

        node_mlp_pool_kernel<<<(N + 255) / 256, 256, 0, stream>>>(
            (const float4*)x, (const float4*)agg, batch, eps, W1, b1, W2, b2,
            gsum, gcnt, N);

        pool_softmax_kernel<<<(NUM_GRAPHS + 255) / 256, 256, 0, stream>>>(
            gsum, gcnt, (float*)d_out);
    }
}

// Round 7
// 480.673 us; speedup vs baseline: 1.4289x; 1.0733x over previous
//
#include <hip/hip_runtime.h>

#define NUM_GRAPHS 1024
#define BIN_BITS 10
#define BIN_SIZE (1 << BIN_BITS)      // 1024 nodes per bin
#define EB 8192                       // edges per binning block
#define STH 512                       // scatter threads (8 waves)
#define EPT 16                        // edges per thread in scatter (EB/STH)
#define ATH 1024                      // accum threads (= nodes per bin)
#define ACH 8192                      // accum chunk edges
#define AEPT (ACH / ATH)              // 8 edges per thread per chunk

// ---------------------------------------------------------------------------
// Init: cursors to bin bases, zero pool accumulators.
// ---------------------------------------------------------------------------
__global__ void init_kernel(int* __restrict__ cursor, float* __restrict__ gsum,
                            float* __restrict__ gcnt, int cap) {
    int t = threadIdx.x;  // 1024
    if (t < 512) cursor[t] = t * cap;
    for (int j = t; j < NUM_GRAPHS * 4; j += 1024) gsum[j] = 0.0f;
    for (int j = t; j < NUM_GRAPHS; j += 1024) gcnt[j] = 0.0f;
}

// ---------------------------------------------------------------------------
// x -> packed bf16x4 (8 B/node, 3.8 MB total: fits in ONE XCD L2, so the
// accum gather becomes L2-resident on every XCD without phase tricks).
// ---------------------------------------------------------------------------
__device__ inline unsigned bf16_rn(float f) {
    unsigned u = __float_as_uint(f);
    return (u + 0x7FFFu + ((u >> 16) & 1u)) >> 16;
}
__global__ void x_to_bf16_kernel(const float4* __restrict__ x,
                                 uint2* __restrict__ x16, int N) {
    int i = blockIdx.x * blockDim.x + threadIdx.x;
    if (i >= N) return;
    float4 v = x[i];
    uint2 r;
    r.x = bf16_rn(v.x) | (bf16_rn(v.y) << 16);
    r.y = bf16_rn(v.z) | (bf16_rn(v.w) << 16);
    x16[i] = r;
}

// ---------------------------------------------------------------------------
// bin_scatter v4: rtn-atomic histogram pass (16M lane-atomics), placement by
// plain LDS writes. ALL private arrays use COMPILE-TIME indices (r6's runtime
// indices demoted them to scratch -> ~256 MB spill traffic; VGPR_Count=28
// was the tell). Invalid slots marked bl[i] = -1.
// packed = (dst_local << 19) | src   (src < 2^19, dst_local < 2^10).
// ---------------------------------------------------------------------------
__global__ void __launch_bounds__(STH) bin_scatter(const int* __restrict__ src,
                                                   const int* __restrict__ dst,
                                                   int* __restrict__ packed,
                                                   int* __restrict__ cursor,
                                                   int E, int cap, int nb) {
    __shared__ int shist[512];     // per-bin counts (via rtn atomics)
    __shared__ int sprefix[513];   // prefix of counts
    __shared__ int sgbase[512];    // global base per bin (this block's slot)
    __shared__ int spacked[EB];    // bin-sorted packed edges (32 KB)
    __shared__ int wsum[8];

    const int t = threadIdx.x;
    const int lane = t & 63;
    const int wave = t >> 6;
    const int b0 = blockIdx.x * EB;
    const int myBase = b0 + t * EPT;

    for (int j = t; j < 512; j += STH) shist[j] = 0;
    __syncthreads();

    // ---- pass A: rtn-atomic count; (bin,lpos)+packed stay in REGISTERS ----
    int pv[EPT];                   // packed edge values
    int bl[EPT];                   // (bin << 13) | lpos, or -1 if invalid
    const bool full = (myBase + EPT <= E);
    if (full) {
#pragma unroll
        for (int v = 0; v < EPT / 4; ++v) {
            int4 d = *(const int4*)(dst + myBase + v * 4);
            int4 s = *(const int4*)(src + myBase + v * 4);
            int bn, lp;
            bn = ((unsigned)d.x) >> BIN_BITS; lp = atomicAdd(&shist[bn], 1);
            pv[v * 4 + 0] = ((d.x & (BIN_SIZE - 1)) << 19) | s.x;
            bl[v * 4 + 0] = (bn << 13) | lp;
            bn = ((unsigned)d.y) >> BIN_BITS; lp = atomicAdd(&shist[bn], 1);
            pv[v * 4 + 1] = ((d.y & (BIN_SIZE - 1)) << 19) | s.y;
            bl[v * 4 + 1] = (bn << 13) | lp;
            bn = ((unsigned)d.z) >> BIN_BITS; lp = atomicAdd(&shist[bn], 1);
            pv[v * 4 + 2] = ((d.z & (BIN_SIZE - 1)) << 19) | s.z;
            bl[v * 4 + 2] = (bn << 13) | lp;
            bn = ((unsigned)d.w) >> BIN_BITS; lp = atomicAdd(&shist[bn], 1);
            pv[v * 4 + 3] = ((d.w & (BIN_SIZE - 1)) << 19) | s.w;
            bl[v * 4 + 3] = (bn << 13) | lp;
        }
    } else {
#pragma unroll
        for (int i = 0; i < EPT; ++i) {
            int e = myBase + i;
            bool ok = e < E;
            int d = ok ? dst[e] : 0;
            int s = ok ? src[e] : 0;
            int bn = ((unsigned)d) >> BIN_BITS;
            int lp = 0;
            if (ok) lp = atomicAdd(&shist[bn], 1);
            pv[i] = ((d & (BIN_SIZE - 1)) << 19) | s;
            bl[i] = ok ? ((bn << 13) | lp) : -1;
        }
    }
    __syncthreads();

    // ---- prefix scan of 512 counts (shfl within wave + cross-wave) ----
    {
        int v = shist[t];
        int inc = v;
#pragma unroll
        for (int off = 1; off < 64; off <<= 1) {
            int u = __shfl_up(inc, off);
            if (lane >= off) inc += u;
        }
        if (lane == 63) wsum[wave] = inc;
        __syncthreads();
        if (t == 0) {
            int acc = 0;
#pragma unroll
            for (int w = 0; w < 8; ++w) { int c = wsum[w]; wsum[w] = acc; acc += c; }
        }
        __syncthreads();
        sprefix[t + 1] = inc + wsum[wave];     // inclusive prefix at t
        if (t == 0) sprefix[0] = 0;
        if (t < nb && v > 0) sgbase[t] = atomicAdd(&cursor[t], v);
    }
    __syncthreads();

    // ---- pass B: place from registers — plain LDS writes, no atomics ----
    if (full) {
#pragma unroll
        for (int i = 0; i < EPT; ++i) {
            int bn = ((unsigned)bl[i]) >> 13;
            int lp = bl[i] & 0x1FFF;
            spacked[sprefix[bn] + lp] = pv[i];
        }
    } else {
#pragma unroll
        for (int i = 0; i < EPT; ++i) {
            if (bl[i] >= 0) {
                int bn = ((unsigned)bl[i]) >> 13;
                int lp = bl[i] & 0x1FFF;
                spacked[sprefix[bn] + lp] = pv[i];
            }
        }
    }
    __syncthreads();

    // ---- flush: bin segments -> contiguous global regions (coalesced, nt) ----
    int cnt = sprefix[nb < 512 ? nb : 512];
    int totE = E - b0; if (totE < 0) totE = 0;
    if (cnt > totE) cnt = totE;
    for (int j = t; j < cnt; j += STH) {
        int lo = 0, hi = nb;
        while (hi - lo > 1) {
            int mid = (lo + hi) >> 1;
            if (sprefix[mid] <= j) lo = mid; else hi = mid;
        }
        int pos = sgbase[lo] + (j - sprefix[lo]);
        if (pos < (lo + 1) * cap)              // overflow guard (~28 sigma)
            __builtin_nontemporal_store(spacked[j], &packed[pos]);
    }
}

// ---------------------------------------------------------------------------
// Accum v4 + MLP + pool, one block per bin. Per 8192-edge chunk: rtn-atomic
// histogram over dst_local (16M atomics total) -> prefix scan -> place src
// (plain LDS writes, compile-time reg indices) -> thread t consumes its
// node's segment, gathering bf16x4 x16[src] (L2-resident) into registers.
// ---------------------------------------------------------------------------
__global__ void __launch_bounds__(ATH) bin_accum_mlp_pool(
        const float4* __restrict__ x,
        const uint2* __restrict__ x16,
        const int* __restrict__ packed,
        const int* __restrict__ cursor,
        const int* __restrict__ batch,
        const float* __restrict__ eps_p,
        const float* __restrict__ W1, const float* __restrict__ b1,
        const float* __restrict__ W2, const float* __restrict__ b2,
        float* __restrict__ gsum, float* __restrict__ gcnt,
        int N, int cap) {
    __shared__ int srt[ACH];            // 32 KB: src ids sorted by dst_local
    __shared__ int hist[BIN_SIZE];      // 4 KB
    __shared__ int pfx[BIN_SIZE + 1];   // 4 KB
    __shared__ int wsum[16];

    const int bin = blockIdx.x;
    const int t = threadIdx.x;
    const int lane = t & 63;
    const int wave = t >> 6;

    const int start = bin * cap;
    int end = cursor[bin];
    if (end > start + cap) end = start + cap;

    float a0 = 0.f, a1 = 0.f, a2 = 0.f, a3 = 0.f;   // agg for node bin*1024+t

#pragma unroll 1
    for (int cs = start; cs < end; cs += ACH) {
        int ce = cs + ACH; if (ce > end) ce = end;

        hist[t] = 0;
        __syncthreads();

        // ---- histogram with rtn atomics; COMPILE-TIME reg indices ----
        int dlp[AEPT];   // (dst_local << 13) | lpos, or -1
        int sv[AEPT];    // src id
#pragma unroll
        for (int i = 0; i < AEPT; ++i) {
            int e = cs + i * ATH + t;
            bool ok = e < ce;
            int p = ok ? __builtin_nontemporal_load(&packed[e]) : 0;
            int dl = ((unsigned)p) >> 19;
            int lp = 0;
            if (ok) lp = atomicAdd(&hist[dl], 1);
            dlp[i] = ok ? ((dl << 13) | lp) : -1;
            sv[i] = p & 0x7FFFF;
        }
        __syncthreads();

        // ---- prefix scan over 1024 counts ----
        {
            int v = hist[t];
            int inc = v;
#pragma unroll
            for (int off = 1; off < 64; off <<= 1) {
                int u = __shfl_up(inc, off);
                if (lane >= off) inc += u;
            }
            if (lane == 63) wsum[wave] = inc;
            __syncthreads();
            if (t == 0) {
                int acc = 0;
#pragma unroll
                for (int w = 0; w < 16; ++w) { int c = wsum[w]; wsum[w] = acc; acc += c; }
            }
            __syncthreads();
            pfx[t + 1] = inc + wsum[wave];
            if (t == 0) pfx[0] = 0;
        }
        __syncthreads();

        // ---- place src ids sorted by dst_local — plain LDS writes ----
#pragma unroll
        for (int i = 0; i < AEPT; ++i) {
            if (dlp[i] >= 0) {
                int dl = ((unsigned)dlp[i]) >> 13;
                int lp = dlp[i] & 0x1FFF;
                srt[pfx[dl] + lp] = sv[i];
            }
        }
        __syncthreads();

        // ---- consume own segment: bf16x4 gather (L2-resident, 8 B) ----
        int jb = pfx[t], je = pfx[t + 1];
        for (int j = jb; j < je; ++j) {
            uint2 v = x16[srt[j]];
            a0 += __uint_as_float(v.x << 16);
            a1 += __uint_as_float(v.x & 0xFFFF0000u);
            a2 += __uint_as_float(v.y << 16);
            a3 += __uint_as_float(v.y & 0xFFFF0000u);
        }
        __syncthreads();   // protect srt/hist before next chunk
    }

    // ---- MLP + pool from register accumulator (self term in f32) ----
    int n = bin * BIN_SIZE + t;           // one node per thread
    bool valid = n < N;
    float o0 = 0.f, o1 = 0.f, o2 = 0.f, o3 = 0.f;
    int g = -1;
    if (valid) {
        float eps = eps_p[0];
        float4 xv = x[n];
        float h0 = (1.0f + eps) * xv.x + a0;
        float h1 = (1.0f + eps) * xv.y + a1;
        float h2 = (1.0f + eps) * xv.z + a2;
        float h3 = (1.0f + eps) * xv.w + a3;

        float tmp[16];
#pragma unroll
        for (int j = 0; j < 16; ++j) {
            float v = b1[j] + h0 * W1[j] + h1 * W1[16 + j] + h2 * W1[32 + j] + h3 * W1[48 + j];
            tmp[j] = v > 0.0f ? v : 0.0f;
        }
        float o[4];
#pragma unroll
        for (int j = 0; j < 4; ++j) {
            float v = b2[j];
#pragma unroll
            for (int k = 0; k < 16; ++k) v += tmp[k] * W2[k * 4 + j];
            o[j] = v > 0.0f ? v : 0.0f;
        }
        o0 = o[0]; o1 = o[1]; o2 = o[2]; o3 = o[3];
        g = batch[n];
    }

    // batch is sorted -> waves almost always graph-uniform
    int g0 = __shfl(g, 0);
    bool uni = __all(g == g0);
    if (uni && g0 >= 0) {
#pragma unroll
        for (int off = 32; off > 0; off >>= 1) {
            o0 += __shfl_down(o0, off);
            o1 += __shfl_down(o1, off);
            o2 += __shfl_down(o2, off);
            o3 += __shfl_down(o3, off);
        }
        if ((t & 63) == 0) {
            unsafeAtomicAdd(&gsum[(size_t)g0 * 4 + 0], o0);
            unsafeAtomicAdd(&gsum[(size_t)g0 * 4 + 1], o1);
            unsafeAtomicAdd(&gsum[(size_t)g0 * 4 + 2], o2);
            unsafeAtomicAdd(&gsum[(size_t)g0 * 4 + 3], o3);
            unsafeAtomicAdd(&gcnt[g0], 64.0f);
        }
    } else if (valid) {
        unsafeAtomicAdd(&gsum[(size_t)g * 4 + 0], o0);
        unsafeAtomicAdd(&gsum[(size_t)g * 4 + 1], o1);
        unsafeAtomicAdd(&gsum[(size_t)g * 4 + 2], o2);
        unsafeAtomicAdd(&gsum[(size_t)g * 4 + 3], o3);
        unsafeAtomicAdd(&gcnt[g], 1.0f);
    }
}

// ---------------------------------------------------------------------------
// pooled = sums / max(cnt,1); out = log_softmax per graph.
// ---------------------------------------------------------------------------
__global__ void pool_softmax_kernel(const float* __restrict__ gsum,
                                    const float* __restrict__ gcnt,
                                    float* __restrict__ out) {
    int g = blockIdx.x * blockDim.x + threadIdx.x;
    if (g >= NUM_GRAPHS) return;
    float c = fmaxf(gcnt[g], 1.0f);
    float p0 = gsum[g * 4 + 0] / c;
    float p1 = gsum[g * 4 + 1] / c;
    float p2 = gsum[g * 4 + 2] / c;
    float p3 = gsum[g * 4 + 3] / c;
    float m = fmaxf(fmaxf(p0, p1), fmaxf(p2, p3));
    float s = expf(p0 - m) + expf(p1 - m) + expf(p2 - m) + expf(p3 - m);
    float lse = m + logf(s);
    out[g * 4 + 0] = p0 - lse;
    out[g * 4 + 1] = p1 - lse;
    out[g * 4 + 2] = p2 - lse;
    out[g * 4 + 3] = p3 - lse;
}

// ---------------------------------------------------------------------------
// Fallback kernels (ws too small): direct atomic scatter + separate MLP/pool.
// ---------------------------------------------------------------------------
__global__ void edge_scatter_kernel(const float4* __restrict__ x,
                                    const int* __restrict__ src,
                                    const int* __restrict__ dst,
                                    float* __restrict__ agg,
                                    int E) {
    int t = blockIdx.x * blockDim.x + threadIdx.x;
    int e = t * 4;
    if (e + 3 < E) {
        int4 s = *(const int4*)(src + e);
        int4 d = *(const int4*)(dst + e);
        float4 xv;
        xv = x[s.x];
        unsafeAtomicAdd(&agg[(size_t)d.x * 4 + 0], xv.x);
        unsafeAtomicAdd(&agg[(size_t)d.x * 4 + 1], xv.y);
        unsafeAtomicAdd(&agg[(size_t)d.x * 4 + 2], xv.z);
        unsafeAtomicAdd(&agg[(size_t)d.x * 4 + 3], xv.w);
        xv = x[s.y];
        unsafeAtomicAdd(&agg[(size_t)d.y * 4 + 0], xv.x);
        unsafeAtomicAdd(&agg[(size_t)d.y * 4 + 1], xv.y);
        unsafeAtomicAdd(&agg[(size_t)d.y * 4 + 2], xv.z);
        unsafeAtomicAdd(&agg[(size_t)d.y * 4 + 3], xv.w);
        xv = x[s.z];
        unsafeAtomicAdd(&agg[(size_t)d.z * 4 + 0], xv.x);
        unsafeAtomicAdd(&agg[(size_t)d.z * 4 + 1], xv.y);
        unsafeAtomicAdd(&agg[(size_t)d.z * 4 + 2], xv.z);
        unsafeAtomicAdd(&agg[(size_t)d.z * 4 + 3], xv.w);
        xv = x[s.w];
        unsafeAtomicAdd(&agg[(size_t)d.w * 4 + 0], xv.x);
        unsafeAtomicAdd(&agg[(size_t)d.w * 4 + 1], xv.y);
        unsafeAtomicAdd(&agg[(size_t)d.w * 4 + 2], xv.z);
        unsafeAtomicAdd(&agg[(size_t)d.w * 4 + 3], xv.w);
    } else {
        for (int i = e; i < E; ++i) {
            int sv = src[i], dv = dst[i];
            float4 xv = x[sv];
            unsafeAtomicAdd(&agg[(size_t)dv * 4 + 0], xv.x);
            unsafeAtomicAdd(&agg[(size_t)dv * 4 + 1], xv.y);
            unsafeAtomicAdd(&agg[(size_t)dv * 4 + 2], xv.z);
            unsafeAtomicAdd(&agg[(size_t)dv * 4 + 3], xv.w);
        }
    }
}

__global__ void node_mlp_pool_kernel(const float4* __restrict__ x,
                                     const float4* __restrict__ agg,
                                     const int* __restrict__ batch,
                                     const float* __restrict__ eps_p,
                                     const float* __restrict__ W1,
                                     const float* __restrict__ b1,
                                     const float* __restrict__ W2,
                                     const float* __restrict__ b2,
                                     float* __restrict__ gsum,
                                     float* __restrict__ gcnt,
                                     int N) {
    int i = blockIdx.x * blockDim.x + threadIdx.x;
    bool valid = i < N;
    float o0 = 0.f, o1 = 0.f, o2 = 0.f, o3 = 0.f;
    int g = -1;
    if (valid) {
        float eps = eps_p[0];
        float4 xv = x[i];
        float4 av = agg[i];
        float h0 = (1.0f + eps) * xv.x + av.x;
        float h1 = (1.0f + eps) * xv.y + av.y;
        float h2 = (1.0f + eps) * xv.z + av.z;
        float h3 = (1.0f + eps) * xv.w + av.w;
        float tmp[16];
#pragma unroll
        for (int j = 0; j < 16; ++j) {
            float v = b1[j] + h0 * W1[j] + h1 * W1[16 + j] + h2 * W1[32 + j] + h3 * W1[48 + j];
            tmp[j] = v > 0.0f ? v : 0.0f;
        }
        float o[4];
#pragma unroll
        for (int j = 0; j < 4; ++j) {
            float v = b2[j];
#pragma unroll
            for (int k = 0; k < 16; ++k) v += tmp[k] * W2[k * 4 + j];
            o[j] = v > 0.0f ? v : 0.0f;
        }
        o0 = o[0]; o1 = o[1]; o2 = o[2]; o3 = o[3];
        g = batch[i];
    }
    int g0 = __shfl(g, 0);
    bool uni = __all(g == g0);
    if (uni && g0 >= 0) {
#pragma unroll
        for (int off = 32; off > 0; off >>= 1) {
            o0 += __shfl_down(o0, off);
            o1 += __shfl_down(o1, off);
            o2 += __shfl_down(o2, off);
            o3 += __shfl_down(o3, off);
        }
        if ((threadIdx.x & 63) == 0) {
            unsafeAtomicAdd(&gsum[(size_t)g0 * 4 + 0], o0);
            unsafeAtomicAdd(&gsum[(size_t)g0 * 4 + 1], o1);
            unsafeAtomicAdd(&gsum[(size_t)g0 * 4 + 2], o2);
            unsafeAtomicAdd(&gsum[(size_t)g0 * 4 + 3], o3);
            unsafeAtomicAdd(&gcnt[g0], 64.0f);
        }
    } else if (valid) {
        unsafeAtomicAdd(&gsum[(size_t)g * 4 + 0], o0);
        unsafeAtomicAdd(&gsum[(size_t)g * 4 + 1], o1);
        unsafeAtomicAdd(&gsum[(size_t)g * 4 + 2], o2);
        unsafeAtomicAdd(&gsum[(size_t)g * 4 + 3], o3);
        unsafeAtomicAdd(&gcnt[g], 1.0f);
    }
}

extern "C" void kernel_launch(void* const* d_in, const int* in_sizes, int n_in,
                              void* d_out, int out_size, void* d_ws, size_t ws_size,
                              hipStream_t stream) {
    const float* x     = (const float*)d_in[0];
    const int*   ei    = (const int*)d_in[1];
    const int*   batch = (const int*)d_in[2];
    const float* eps   = (const float*)d_in[3];
    const float* W1    = (const float*)d_in[4];
    const float* b1    = (const float*)d_in[5];
    const float* W2    = (const float*)d_in[6];
    const float* b2    = (const float*)d_in[7];

    const int N = in_sizes[0] / 4;
    const int E = in_sizes[1] / 2;
    const int* src = ei;
    const int* dst = ei + (size_t)E;

    const int nb = (N + BIN_SIZE - 1) >> BIN_BITS;   // 489 for N=500K
    const int epb = (E + nb - 1) / nb;
    const int cap = epb + epb / 8 + 1024;            // ~28 sigma headroom

    // Fast-path ws layout: x16 [2N] | packed [nb*cap] | cursor [512] |
    //                      gsum [G*4] | gcnt [G]      (4 B units)
    size_t x16_elems = ((size_t)2 * N + 3) & ~(size_t)3;
    size_t packed_elems = ((size_t)nb * cap + 3) & ~(size_t)3;
    size_t need = (x16_elems + packed_elems + 512 + NUM_GRAPHS * 5) * sizeof(float);

    if (nb <= 512 && N < (1 << 19) && need <= ws_size) {
        uint2* x16    = (uint2*)d_ws;
        int*   packed = (int*)d_ws + x16_elems;
        int*   cursor = packed + packed_elems;
        float* gsum   = (float*)(cursor + 512);
        float* gcnt   = gsum + (size_t)NUM_GRAPHS * 4;

        init_kernel<<<1, 1024, 0, stream>>>(cursor, gsum, gcnt, cap);

        x_to_bf16_kernel<<<(N + 511) / 512, 512, 0, stream>>>(
            (const float4*)x, x16, N);

        int nblocks_e = (E + EB - 1) / EB;
        bin_scatter<<<nblocks_e, STH, 0, stream>>>(src, dst, packed, cursor, E, cap, nb);

        bin_accum_mlp_pool<<<nb, ATH, 0, stream>>>(
            (const float4*)x, (const uint2*)x16, packed, cursor, batch, eps,
            W1, b1, W2, b2, gsum, gcnt, N, cap);

        pool_softmax_kernel<<<(NUM_GRAPHS + 255) / 256, 256, 0, stream>>>(
            gsum, gcnt, (float*)d_out);
    } else {
        float* agg  = (float*)d_ws;
        float* gsum = agg + (size_t)N * 4;
        float* gcnt = gsum + (size_t)NUM_GRAPHS * 4;
        size_t zero_bytes = ((size_t)N * 4 + NUM_GRAPHS * 5) * sizeof(float);
        (void)hipMemsetAsync(d_ws, 0, zero_bytes, stream);

        int e4 = (E + 3) / 4;
        edge_scatter_kernel<<<(e4 + 255) / 256, 256, 0, stream>>>(
            (const float4*)x, src, dst, agg, E);

        node_mlp_pool_kernel<<<(N + 255) / 256, 256, 0, stream>>>(
            (const float4*)x, (const float4*)agg, batch, eps, W1, b1, W2, b2,
            gsum, gcnt, N);

        pool_softmax_kernel<<<(NUM_GRAPHS + 255) / 256, 256, 0, stream>>>(
            gsum, gcnt, (float*)d_out);
    }
}

// Round 9
// 450.119 us; speedup vs baseline: 1.5259x; 1.0679x over previous
//
#include <hip/hip_runtime.h>

#define NUM_GRAPHS 1024
#define BIN_BITS 10
#define BIN_SIZE (1 << BIN_BITS)      // 1024 nodes per bin
#define EB 8192                       // edges per binning block
#define STH 512                       // scatter threads (8 waves)
#define EPT 16                        // edges per thread in scatter (EB/STH)
#define ATH 1024                      // accum threads (= nodes per bin)
#define ACH 8192                      // accum chunk edges
#define AEPT (ACH / ATH)              // 8 edges per thread per chunk

typedef int v4i __attribute__((ext_vector_type(4)));  // native vec for nt-load

// ---------------------------------------------------------------------------
// Prep: cursors to bin bases, zero pool accumulators, x -> packed bf16x4
// (8 B/node, 3.8 MB: fits every XCD L2 -> accum gather is cache-resident).
// ---------------------------------------------------------------------------
__device__ inline unsigned bf16_rn(float f) {
    unsigned u = __float_as_uint(f);
    return (u + 0x7FFFu + ((u >> 16) & 1u)) >> 16;
}
__global__ void prep_kernel(const float4* __restrict__ x, uint2* __restrict__ x16,
                            int N, int* __restrict__ cursor,
                            float* __restrict__ gsum, float* __restrict__ gcnt,
                            int cap) {
    int i = blockIdx.x * blockDim.x + threadIdx.x;
    if (i < 512) cursor[i] = i * cap;
    if (i < NUM_GRAPHS * 4) gsum[i] = 0.0f;
    if (i < NUM_GRAPHS) gcnt[i] = 0.0f;
    if (i < N) {
        float4 v = x[i];
        uint2 r;
        r.x = bf16_rn(v.x) | (bf16_rn(v.y) << 16);
        r.y = bf16_rn(v.z) | (bf16_rn(v.w) << 16);
        x16[i] = r;
    }
}

// ---------------------------------------------------------------------------
// bin_scatter v5: rtn-atomic histogram pass (16M lane-atomics ~ the floor),
// placement by plain LDS writes; placement co-writes sbin[slot]=bin so the
// flush needs NO binary search (was 9 divergent LDS reads per edge).
// All private arrays use compile-time indices (r6 spill lesson).
// packed = (dst_local << 19) | src   (src < 2^19, dst_local < 2^10).
// ---------------------------------------------------------------------------
__global__ void __launch_bounds__(STH) bin_scatter(const int* __restrict__ src,
                                                   const int* __restrict__ dst,
                                                   int* __restrict__ packed,
                                                   int* __restrict__ cursor,
                                                   int E, int cap, int nb) {
    __shared__ int shist[512];              // per-bin counts (rtn atomics)
    __shared__ int sprefix[513];            // prefix of counts
    __shared__ int sgbase[512];             // global base per bin
    __shared__ int spacked[EB];             // bin-sorted packed edges (32 KB)
    __shared__ unsigned short sbin[EB];     // bin id per sorted slot (16 KB)
    __shared__ int wsum[8];

    const int t = threadIdx.x;
    const int lane = t & 63;
    const int wave = t >> 6;
    const int b0 = blockIdx.x * EB;
    const int myBase = b0 + t * EPT;

    for (int j = t; j < 512; j += STH) shist[j] = 0;
    __syncthreads();

    // ---- pass A: rtn-atomic count; (bin,lpos)+packed stay in REGISTERS ----
    int pv[EPT];                   // packed edge values
    int bl[EPT];                   // (bin << 13) | lpos, or -1 if invalid
    const bool full = (myBase + EPT <= E);
    if (full) {
#pragma unroll
        for (int v = 0; v < EPT / 4; ++v) {
            int4 d = *(const int4*)(dst + myBase + v * 4);
            int4 s = *(const int4*)(src + myBase + v * 4);
            int bn, lp;
            bn = ((unsigned)d.x) >> BIN_BITS; lp = atomicAdd(&shist[bn], 1);
            pv[v * 4 + 0] = ((d.x & (BIN_SIZE - 1)) << 19) | s.x;
            bl[v * 4 + 0] = (bn << 13) | lp;
            bn = ((unsigned)d.y) >> BIN_BITS; lp = atomicAdd(&shist[bn], 1);
            pv[v * 4 + 1] = ((d.y & (BIN_SIZE - 1)) << 19) | s.y;
            bl[v * 4 + 1] = (bn << 13) | lp;
            bn = ((unsigned)d.z) >> BIN_BITS; lp = atomicAdd(&shist[bn], 1);
            pv[v * 4 + 2] = ((d.z & (BIN_SIZE - 1)) << 19) | s.z;
            bl[v * 4 + 2] = (bn << 13) | lp;
            bn = ((unsigned)d.w) >> BIN_BITS; lp = atomicAdd(&shist[bn], 1);
            pv[v * 4 + 3] = ((d.w & (BIN_SIZE - 1)) << 19) | s.w;
            bl[v * 4 + 3] = (bn << 13) | lp;
        }
    } else {
#pragma unroll
        for (int i = 0; i < EPT; ++i) {
            int e = myBase + i;
            bool ok = e < E;
            int d = ok ? dst[e] : 0;
            int s = ok ? src[e] : 0;
            int bn = ((unsigned)d) >> BIN_BITS;
            int lp = 0;
            if (ok) lp = atomicAdd(&shist[bn], 1);
            pv[i] = ((d & (BIN_SIZE - 1)) << 19) | s;
            bl[i] = ok ? ((bn << 13) | lp) : -1;
        }
    }
    __syncthreads();

    // ---- prefix scan of 512 counts (shfl within wave + cross-wave) ----
    {
        int v = shist[t];
        int inc = v;
#pragma unroll
        for (int off = 1; off < 64; off <<= 1) {
            int u = __shfl_up(inc, off);
            if (lane >= off) inc += u;
        }
        if (lane == 63) wsum[wave] = inc;
        __syncthreads();
        if (t == 0) {
            int acc = 0;
#pragma unroll
            for (int w = 0; w < 8; ++w) { int c = wsum[w]; wsum[w] = acc; acc += c; }
        }
        __syncthreads();
        sprefix[t + 1] = inc + wsum[wave];     // inclusive prefix at t
        if (t == 0) sprefix[0] = 0;
        if (t < nb && v > 0) sgbase[t] = atomicAdd(&cursor[t], v);
    }
    __syncthreads();

    // ---- pass B: place from registers — plain LDS writes, no atomics ----
    if (full) {
#pragma unroll
        for (int i = 0; i < EPT; ++i) {
            int bn = ((unsigned)bl[i]) >> 13;
            int lp = bl[i] & 0x1FFF;
            int idx = sprefix[bn] + lp;
            spacked[idx] = pv[i];
            sbin[idx] = (unsigned short)bn;
        }
    } else {
#pragma unroll
        for (int i = 0; i < EPT; ++i) {
            if (bl[i] >= 0) {
                int bn = ((unsigned)bl[i]) >> 13;
                int lp = bl[i] & 0x1FFF;
                int idx = sprefix[bn] + lp;
                spacked[idx] = pv[i];
                sbin[idx] = (unsigned short)bn;
            }
        }
    }
    __syncthreads();

    // ---- flush: table lookup instead of binary search ----
    int cnt = sprefix[nb < 512 ? nb : 512];
    int totE = E - b0; if (totE < 0) totE = 0;
    if (cnt > totE) cnt = totE;
    for (int j = t; j < cnt; j += STH) {
        int bn = sbin[j];
        int pos = sgbase[bn] + (j - sprefix[bn]);
        if (pos < (bn + 1) * cap)              // overflow guard (~28 sigma)
            __builtin_nontemporal_store(spacked[j], &packed[pos]);
    }
}

// ---------------------------------------------------------------------------
// Accum v5 + MLP + pool, one block per bin. Per 8192-edge chunk: rtn-atomic
// histogram over dst_local (16M atomics, the floor) -> prefix scan -> place
// src (plain LDS writes) -> thread t consumes its node's segment, gathering
// bf16x4 x16[src] (L2-resident). Packed read via 16B nt loads through a
// native ext_vector_type (HIP's int4 class is rejected by the builtin).
// ---------------------------------------------------------------------------
__global__ void __launch_bounds__(ATH) bin_accum_mlp_pool(
        const float4* __restrict__ x,
        const uint2* __restrict__ x16,
        const int* __restrict__ packed,
        const int* __restrict__ cursor,
        const int* __restrict__ batch,
        const float* __restrict__ eps_p,
        const float* __restrict__ W1, const float* __restrict__ b1,
        const float* __restrict__ W2, const float* __restrict__ b2,
        float* __restrict__ gsum, float* __restrict__ gcnt,
        int N, int cap) {
    __shared__ int srt[ACH];            // 32 KB: src ids sorted by dst_local
    __shared__ int hist[BIN_SIZE];      // 4 KB
    __shared__ int pfx[BIN_SIZE + 1];   // 4 KB
    __shared__ int wsum[16];

    const int bin = blockIdx.x;
    const int t = threadIdx.x;
    const int lane = t & 63;
    const int wave = t >> 6;

    const int start = bin * cap;
    int end = cursor[bin];
    if (end > start + cap) end = start + cap;

    float a0 = 0.f, a1 = 0.f, a2 = 0.f, a3 = 0.f;   // agg for node bin*1024+t

#pragma unroll 1
    for (int cs = start; cs < end; cs += ACH) {
        int ce = cs + ACH; if (ce > end) ce = end;

        hist[t] = 0;
        __syncthreads();

        // ---- histogram with rtn atomics; 16B nt loads; reg indices ----
        int dlp[AEPT];   // (dst_local << 13) | lpos, or -1
        int sv[AEPT];    // src id
#pragma unroll
        for (int i = 0; i < AEPT / 4; ++i) {
            int ebase = cs + (i * ATH + t) * 4;
            v4i p4;
            if (ebase + 3 < ce) {
                p4 = __builtin_nontemporal_load((const v4i*)(packed + ebase));
            } else {
                p4.x = (ebase + 0 < ce) ? packed[ebase + 0] : 0;
                p4.y = (ebase + 1 < ce) ? packed[ebase + 1] : 0;
                p4.z = (ebase + 2 < ce) ? packed[ebase + 2] : 0;
                p4.w = (ebase + 3 < ce) ? packed[ebase + 3] : 0;
            }
#pragma unroll
            for (int k = 0; k < 4; ++k) {
                int p = (k == 0) ? p4.x : (k == 1) ? p4.y : (k == 2) ? p4.z : p4.w;
                bool ok = (ebase + k) < ce;
                int dl = ((unsigned)p) >> 19;
                int lp = 0;
                if (ok) lp = atomicAdd(&hist[dl], 1);
                dlp[i * 4 + k] = ok ? ((dl << 13) | lp) : -1;
                sv[i * 4 + k] = p & 0x7FFFF;
            }
        }
        __syncthreads();

        // ---- prefix scan over 1024 counts ----
        {
            int v = hist[t];
            int inc = v;
#pragma unroll
            for (int off = 1; off < 64; off <<= 1) {
                int u = __shfl_up(inc, off);
                if (lane >= off) inc += u;
            }
            if (lane == 63) wsum[wave] = inc;
            __syncthreads();
            if (t == 0) {
                int acc = 0;
#pragma unroll
                for (int w = 0; w < 16; ++w) { int c = wsum[w]; wsum[w] = acc; acc += c; }
            }
            __syncthreads();
            pfx[t + 1] = inc + wsum[wave];
            if (t == 0) pfx[0] = 0;
        }
        __syncthreads();

        // ---- place src ids sorted by dst_local — plain LDS writes ----
#pragma unroll
        for (int i = 0; i < AEPT; ++i) {
            if (dlp[i] >= 0) {
                int dl = ((unsigned)dlp[i]) >> 13;
                int lp = dlp[i] & 0x1FFF;
                srt[pfx[dl] + lp] = sv[i];
            }
        }
        __syncthreads();

        // ---- consume own segment: bf16x4 gather (L2-resident, 8 B) ----
        int jb = pfx[t], je = pfx[t + 1];
        for (int j = jb; j < je; ++j) {
            uint2 v = x16[srt[j]];
            a0 += __uint_as_float(v.x << 16);
            a1 += __uint_as_float(v.x & 0xFFFF0000u);
            a2 += __uint_as_float(v.y << 16);
            a3 += __uint_as_float(v.y & 0xFFFF0000u);
        }
        __syncthreads();   // protect srt/hist before next chunk
    }

    // ---- MLP + pool from register accumulator (self term in f32) ----
    int n = bin * BIN_SIZE + t;           // one node per thread
    bool valid = n < N;
    float o0 = 0.f, o1 = 0.f, o2 = 0.f, o3 = 0.f;
    int g = -1;
    if (valid) {
        float eps = eps_p[0];
        float4 xv = x[n];
        float h0 = (1.0f + eps) * xv.x + a0;
        float h1 = (1.0f + eps) * xv.y + a1;
        float h2 = (1.0f + eps) * xv.z + a2;
        float h3 = (1.0f + eps) * xv.w + a3;

        float tmp[16];
#pragma unroll
        for (int j = 0; j < 16; ++j) {
            float v = b1[j] + h0 * W1[j] + h1 * W1[16 + j] + h2 * W1[32 + j] + h3 * W1[48 + j];
            tmp[j] = v > 0.0f ? v : 0.0f;
        }
        float o[4];
#pragma unroll
        for (int j = 0; j < 4; ++j) {
            float v = b2[j];
#pragma unroll
            for (int k = 0; k < 16; ++k) v += tmp[k] * W2[k * 4 + j];
            o[j] = v > 0.0f ? v : 0.0f;
        }
        o0 = o[0]; o1 = o[1]; o2 = o[2]; o3 = o[3];
        g = batch[n];
    }

    // batch is sorted -> waves almost always graph-uniform
    int g0 = __shfl(g, 0);
    bool uni = __all(g == g0);
    if (uni && g0 >= 0) {
#pragma unroll
        for (int off = 32; off > 0; off >>= 1) {
            o0 += __shfl_down(o0, off);
            o1 += __shfl_down(o1, off);
            o2 += __shfl_down(o2, off);
            o3 += __shfl_down(o3, off);
        }
        if ((t & 63) == 0) {
            unsafeAtomicAdd(&gsum[(size_t)g0 * 4 + 0], o0);
            unsafeAtomicAdd(&gsum[(size_t)g0 * 4 + 1], o1);
            unsafeAtomicAdd(&gsum[(size_t)g0 * 4 + 2], o2);
            unsafeAtomicAdd(&gsum[(size_t)g0 * 4 + 3], o3);
            unsafeAtomicAdd(&gcnt[g0], 64.0f);
        }
    } else if (valid) {
        unsafeAtomicAdd(&gsum[(size_t)g * 4 + 0], o0);
        unsafeAtomicAdd(&gsum[(size_t)g * 4 + 1], o1);
        unsafeAtomicAdd(&gsum[(size_t)g * 4 + 2], o2);
        unsafeAtomicAdd(&gsum[(size_t)g * 4 + 3], o3);
        unsafeAtomicAdd(&gcnt[g], 1.0f);
    }
}

// ---------------------------------------------------------------------------
// pooled = sums / max(cnt,1); out = log_softmax per graph.
// ---------------------------------------------------------------------------
__global__ void pool_softmax_kernel(const float* __restrict__ gsum,
                                    const float* __restrict__ gcnt,
                                    float* __restrict__ out) {
    int g = blockIdx.x * blockDim.x + threadIdx.x;
    if (g >= NUM_GRAPHS) return;
    float c = fmaxf(gcnt[g], 1.0f);
    float p0 = gsum[g * 4 + 0] / c;
    float p1 = gsum[g * 4 + 1] / c;
    float p2 = gsum[g * 4 + 2] / c;
    float p3 = gsum[g * 4 + 3] / c;
    float m = fmaxf(fmaxf(p0, p1), fmaxf(p2, p3));
    float s = expf(p0 - m) + expf(p1 - m) + expf(p2 - m) + expf(p3 - m);
    float lse = m + logf(s);
    out[g * 4 + 0] = p0 - lse;
    out[g * 4 + 1] = p1 - lse;
    out[g * 4 + 2] = p2 - lse;
    out[g * 4 + 3] = p3 - lse;
}

// ---------------------------------------------------------------------------
// Fallback kernels (ws too small): direct atomic scatter + separate MLP/pool.
// ---------------------------------------------------------------------------
__global__ void edge_scatter_kernel(const float4* __restrict__ x,
                                    const int* __restrict__ src,
                                    const int* __restrict__ dst,
                                    float* __restrict__ agg,
                                    int E) {
    int t = blockIdx.x * blockDim.x + threadIdx.x;
    int e = t * 4;
    if (e + 3 < E) {
        int4 s = *(const int4*)(src + e);
        int4 d = *(const int4*)(dst + e);
        float4 xv;
        xv = x[s.x];
        unsafeAtomicAdd(&agg[(size_t)d.x * 4 + 0], xv.x);
        unsafeAtomicAdd(&agg[(size_t)d.x * 4 + 1], xv.y);
        unsafeAtomicAdd(&agg[(size_t)d.x * 4 + 2], xv.z);
        unsafeAtomicAdd(&agg[(size_t)d.x * 4 + 3], xv.w);
        xv = x[s.y];
        unsafeAtomicAdd(&agg[(size_t)d.y * 4 + 0], xv.x);
        unsafeAtomicAdd(&agg[(size_t)d.y * 4 + 1], xv.y);
        unsafeAtomicAdd(&agg[(size_t)d.y * 4 + 2], xv.z);
        unsafeAtomicAdd(&agg[(size_t)d.y * 4 + 3], xv.w);
        xv = x[s.z];
        unsafeAtomicAdd(&agg[(size_t)d.z * 4 + 0], xv.x);
        unsafeAtomicAdd(&agg[(size_t)d.z * 4 + 1], xv.y);
        unsafeAtomicAdd(&agg[(size_t)d.z * 4 + 2], xv.z);
        unsafeAtomicAdd(&agg[(size_t)d.z * 4 + 3], xv.w);
        xv = x[s.w];
        unsafeAtomicAdd(&agg[(size_t)d.w * 4 + 0], xv.x);
        unsafeAtomicAdd(&agg[(size_t)d.w * 4 + 1], xv.y);
        unsafeAtomicAdd(&agg[(size_t)d.w * 4 + 2], xv.z);
        unsafeAtomicAdd(&agg[(size_t)d.w * 4 + 3], xv.w);
    } else {
        for (int i = e; i < E; ++i) {
            int sv = src[i], dv = dst[i];
            float4 xv = x[sv];
            unsafeAtomicAdd(&agg[(size_t)dv * 4 + 0], xv.x);
            unsafeAtomicAdd(&agg[(size_t)dv * 4 + 1], xv.y);
            unsafeAtomicAdd(&agg[(size_t)dv * 4 + 2], xv.z);
            unsafeAtomicAdd(&agg[(size_t)dv * 4 + 3], xv.w);
        }
    }
}

__global__ void node_mlp_pool_kernel(const float4* __restrict__ x,
                                     const float4* __restrict__ agg,
                                     const int* __restrict__ batch,
                                     const float* __restrict__ eps_p,
                                     const float* __restrict__ W1,
                                     const float* __restrict__ b1,
                                     const float* __restrict__ W2,
                                     const float* __restrict__ b2,
                                     float* __restrict__ gsum,
                                     float* __restrict__ gcnt,
                                     int N) {
    int i = blockIdx.x * blockDim.x + threadIdx.x;
    bool valid = i < N;
    float o0 = 0.f, o1 = 0.f, o2 = 0.f, o3 = 0.f;
    int g = -1;
    if (valid) {
        float eps = eps_p[0];
        float4 xv = x[i];
        float4 av = agg[i];
        float h0 = (1.0f + eps) * xv.x + av.x;
        float h1 = (1.0f + eps) * xv.y + av.y;
        float h2 = (1.0f + eps) * xv.z + av.z;
        float h3 = (1.0f + eps) * xv.w + av.w;
        float tmp[16];
#pragma unroll
        for (int j = 0; j < 16; ++j) {
            float v = b1[j] + h0 * W1[j] + h1 * W1[16 + j] + h2 * W1[32 + j] + h3 * W1[48 + j];
            tmp[j] = v > 0.0f ? v : 0.0f;
        }
        float o[4];
#pragma unroll
        for (int j = 0; j < 4; ++j) {
            float v = b2[j];
#pragma unroll
            for (int k = 0; k < 16; ++k) v += tmp[k] * W2[k * 4 + j];
            o[j] = v > 0.0f ? v : 0.0f;
        }
        o0 = o[0]; o1 = o[1]; o2 = o[2]; o3 = o[3];
        g = batch[i];
    }
    int g0 = __shfl(g, 0);
    bool uni = __all(g == g0);
    if (uni && g0 >= 0) {
#pragma unroll
        for (int off = 32; off > 0; off >>= 1) {
            o0 += __shfl_down(o0, off);
            o1 += __shfl_down(o1, off);
            o2 += __shfl_down(o2, off);
            o3 += __shfl_down(o3, off);
        }
        if ((threadIdx.x & 63) == 0) {
            unsafeAtomicAdd(&gsum[(size_t)g0 * 4 + 0], o0);
            unsafeAtomicAdd(&gsum[(size_t)g0 * 4 + 1], o1);
            unsafeAtomicAdd(&gsum[(size_t)g0 * 4 + 2], o2);
            unsafeAtomicAdd(&gsum[(size_t)g0 * 4 + 3], o3);
            unsafeAtomicAdd(&gcnt[g0], 64.0f);
        }
    } else if (valid) {
        unsafeAtomicAdd(&gsum[(size_t)g * 4 + 0], o0);
        unsafeAtomicAdd(&gsum[(size_t)g * 4 + 1], o1);
        unsafeAtomicAdd(&gsum[(size_t)g * 4 + 2], o2);
        unsafeAtomicAdd(&gsum[(size_t)g * 4 + 3], o3);
        unsafeAtomicAdd(&gcnt[g], 1.0f);
    }
}

extern "C" void kernel_launch(void* const* d_in, const int* in_sizes, int n_in,
                              void* d_out, int out_size, void* d_ws, size_t ws_size,
                              hipStream_t stream) {
    const float* x     = (const float*)d_in[0];
    const int*   ei    = (const int*)d_in[1];
    const int*   batch = (const int*)d_in[2];
    const float* eps   = (const float*)d_in[3];
    const float* W1    = (const float*)d_in[4];
    const float* b1    = (const float*)d_in[5];
    const float* W2    = (const float*)d_in[6];
    const float* b2    = (const float*)d_in[7];

    const int N = in_sizes[0] / 4;
    const int E = in_sizes[1] / 2;
    const int* src = ei;
    const int* dst = ei + (size_t)E;

    const int nb = (N + BIN_SIZE - 1) >> BIN_BITS;   // 489 for N=500K
    const int epb = (E + nb - 1) / nb;
    int cap = epb + epb / 8 + 1024;                  // ~28 sigma headroom
    cap = (cap + 3) & ~3;                            // 16B-align chunk bases

    // Fast-path ws layout: x16 [2N] | packed [nb*cap] | cursor [512] |
    //                      gsum [G*4] | gcnt [G]      (4 B units)
    size_t x16_elems = ((size_t)2 * N + 3) & ~(size_t)3;
    size_t packed_elems = ((size_t)nb * cap + 3) & ~(size_t)3;
    size_t need = (x16_elems + packed_elems + 512 + NUM_GRAPHS * 5) * sizeof(float);

    if (nb <= 512 && N < (1 << 19) && need <= ws_size) {
        uint2* x16    = (uint2*)d_ws;
        int*   packed = (int*)d_ws + x16_elems;
        int*   cursor = packed + packed_elems;
        float* gsum   = (float*)(cursor + 512);
        float* gcnt   = gsum + (size_t)NUM_GRAPHS * 4;

        prep_kernel<<<(N + 511) / 512, 512, 0, stream>>>(
            (const float4*)x, x16, N, cursor, gsum, gcnt, cap);

        int nblocks_e = (E + EB - 1) / EB;
        bin_scatter<<<nblocks_e, STH, 0, stream>>>(src, dst, packed, cursor, E, cap, nb);

        bin_accum_mlp_pool<<<nb, ATH, 0, stream>>>(
            (const float4*)x, (const uint2*)x16, packed, cursor, batch, eps,
            W1, b1, W2, b2, gsum, gcnt, N, cap);

        pool_softmax_kernel<<<(NUM_GRAPHS + 255) / 256, 256, 0, stream>>>(
            gsum, gcnt, (float*)d_out);
    } else {
        float* agg  = (float*)d_ws;
        float* gsum = agg + (size_t)N * 4;
        float* gcnt = gsum + (size_t)NUM_GRAPHS * 4;
        size_t zero_bytes = ((size_t)N * 4 + NUM_GRAPHS * 5) * sizeof(float);
        (void)hipMemsetAsync(d_ws, 0, zero_bytes, stream);

        int e4 = (E + 3) / 4;
        edge_scatter_kernel<<<(e4 + 255) / 256, 256, 0, stream>>>(
            (const float4*)x, src, dst, agg, E);

        node_mlp_pool_kernel<<<(N + 255) / 256, 256, 0, stream>>>(
            (const float4*)x, (const float4*)agg, batch, eps, W1, b1, W2, b2,
            gsum, gcnt, N);

        pool_softmax_kernel<<<(NUM_GRAPHS + 255) / 256, 256, 0, stream>>>(
            gsum, gcnt, (float*)d_out);
    }
}